// Round 2
// baseline (2309.316 us; speedup 1.0000x reference)
//
#include <hip/hip_runtime.h>

#define kN 100000
#define kH 256
#define kE 3200000
#define kL 4

typedef __attribute__((ext_vector_type(8))) short bf16x8;
typedef __attribute__((ext_vector_type(4))) float f32x4;

static __device__ __forceinline__ float b2f(unsigned short u) {
    return __uint_as_float(((unsigned int)u) << 16);
}
static __device__ __forceinline__ unsigned short f2b(float f) {
    unsigned int u = __float_as_uint(f);
    u = (u + 0x7fffu + ((u >> 16) & 1u)) >> 16;
    return (unsigned short)u;
}

// flags[0]: OR of odd 32-bit words of edge buffer (0 => int64 storage)
// flags[1]: count of even-indexed ushorts of x with bf16-like exponent
//           (> 2^19 of 2^20 sampled => floats stored as bf16)
static __device__ __forceinline__ int is_i64(const int* flags) { return flags[0] == 0; }
static __device__ __forceinline__ int is_bf(const int* flags) { return flags[1] > (1 << 19); }

static __device__ __forceinline__ int eidx(const int* __restrict__ ei, int i64, int pos) {
    return i64 ? ei[2 * pos] : ei[pos];
}

// ---------------- dtype detection ----------------
__global__ __launch_bounds__(256) void detect_kernel(const unsigned int* __restrict__ eiw,
                                                     const unsigned short* __restrict__ xu,
                                                     int* __restrict__ flags) {
    int t = blockIdx.x * 256 + threadIdx.x;  // 2^20 threads total
    unsigned int eor = 0;
    for (int i = t; i < kE; i += (1 << 20)) eor |= eiw[2 * i + 1];
    for (int off = 32; off >= 1; off >>= 1) eor |= __shfl_down(eor, off);
    if ((threadIdx.x & 63) == 0 && eor) atomicOr(&flags[0], 1);
    unsigned short u = xu[2 * t];
    unsigned int e = (u >> 7) & 0xFF;
    if (e >= 101 && e <= 140) atomicAdd(&flags[1], 1);
}

// ---------------- converters (branch on storage flavor) ----------------
__global__ __launch_bounds__(256) void conv_x_kernel(const void* __restrict__ x,
                                                     unsigned short* __restrict__ xb,
                                                     const int* __restrict__ flags) {
    int i = (blockIdx.x * 256 + threadIdx.x) * 4;  // over kN*kH = 25.6M
    if (is_bf(flags)) {
        *(ushort4*)&xb[i] = *(const ushort4*)&((const unsigned short*)x)[i];
    } else {
        float4 v = *(const float4*)&((const float*)x)[i];
        ushort4 o;
        o.x = f2b(v.x); o.y = f2b(v.y); o.z = f2b(v.z); o.w = f2b(v.w);
        *(ushort4*)&xb[i] = o;
    }
}

__global__ __launch_bounds__(256) void conv_w_kernel(const void* __restrict__ Wl,
                                                     const void* __restrict__ Wr,
                                                     unsigned short* __restrict__ wlb,
                                                     unsigned short* __restrict__ wrb,
                                                     const int* __restrict__ flags) {
    int i = (blockIdx.x * 256 + threadIdx.x) * 4;  // over kL*kH*kH = 262144
    if (is_bf(flags)) {
        *(ushort4*)&wlb[i] = *(const ushort4*)&((const unsigned short*)Wl)[i];
        *(ushort4*)&wrb[i] = *(const ushort4*)&((const unsigned short*)Wr)[i];
    } else {
        float4 a = *(const float4*)&((const float*)Wl)[i];
        float4 b = *(const float4*)&((const float*)Wr)[i];
        ushort4 oa, ob;
        oa.x = f2b(a.x); oa.y = f2b(a.y); oa.z = f2b(a.z); oa.w = f2b(a.w);
        ob.x = f2b(b.x); ob.y = f2b(b.y); ob.z = f2b(b.z); ob.w = f2b(b.w);
        *(ushort4*)&wlb[i] = oa;
        *(ushort4*)&wrb[i] = ob;
    }
}

__global__ __launch_bounds__(256) void conv_b_kernel(const void* __restrict__ b,
                                                     float* __restrict__ biasf,
                                                     const int* __restrict__ flags) {
    int i = threadIdx.x * 4;  // over kL*kH = 1024, single block
    if (is_bf(flags)) {
        ushort4 u = *(const ushort4*)&((const unsigned short*)b)[i];
        biasf[i + 0] = b2f(u.x); biasf[i + 1] = b2f(u.y);
        biasf[i + 2] = b2f(u.z); biasf[i + 3] = b2f(u.w);
    } else {
        *(float4*)&biasf[i] = *(const float4*)&((const float*)b)[i];
    }
}

// ---------------- CSR build ----------------
__global__ __launch_bounds__(256) void hist_kernel(const int* __restrict__ ei,
                                                   const int* __restrict__ flags,
                                                   int* __restrict__ deg) {
    int e = blockIdx.x * 256 + threadIdx.x;
    if (e < kE) atomicAdd(&deg[eidx(ei, is_i64(flags), kE + e)], 1);
}

__global__ __launch_bounds__(256) void scan1_kernel(const int* __restrict__ deg,
                                                    int* __restrict__ rowstart,
                                                    int* __restrict__ blocksum) {
    __shared__ int sdata[256];
    int t = threadIdx.x;
    int base = blockIdx.x * 1024 + t * 4;
    int v[4]; int s = 0;
#pragma unroll
    for (int i = 0; i < 4; ++i) {
        v[i] = (base + i < kN) ? deg[base + i] : 0;
        s += v[i];
    }
    sdata[t] = s;
    __syncthreads();
    for (int off = 1; off < 256; off <<= 1) {
        int x = (t >= off) ? sdata[t - off] : 0;
        __syncthreads();
        sdata[t] += x;
        __syncthreads();
    }
    int run = sdata[t] - s;
    if (t == 255) blocksum[blockIdx.x] = sdata[255];
#pragma unroll
    for (int i = 0; i < 4; ++i) {
        if (base + i < kN) rowstart[base + i] = run;
        run += v[i];
    }
}

__global__ void scan2_kernel(int* __restrict__ blocksum, int nb) {
    if (threadIdx.x == 0 && blockIdx.x == 0) {
        int acc = 0;
        for (int i = 0; i < nb; ++i) { int t = blocksum[i]; blocksum[i] = acc; acc += t; }
    }
}

__global__ __launch_bounds__(256) void scan3_kernel(int* __restrict__ rowstart,
                                                    const int* __restrict__ blocksum,
                                                    const int* __restrict__ deg,
                                                    int* __restrict__ cursor,
                                                    float* __restrict__ inv_cnt) {
    int i = blockIdx.x * 256 + threadIdx.x;
    if (i < kN) {
        int rs = rowstart[i] + blocksum[i >> 10];
        rowstart[i] = rs;
        cursor[i] = rs;
        int d = deg[i];
        inv_cnt[i] = 1.0f / (float)(d > 0 ? d : 1);
    }
}

__global__ __launch_bounds__(256) void fill_kernel(const int* __restrict__ ei,
                                                   const int* __restrict__ flags,
                                                   int* __restrict__ cursor,
                                                   int* __restrict__ colidx) {
    int e = blockIdx.x * 256 + threadIdx.x;
    if (e < kE) {
        int i64 = is_i64(flags);
        int s = eidx(ei, i64, e);
        int d = eidx(ei, i64, kE + e);
        int p = atomicAdd(&cursor[d], 1);
        colidx[p] = s;
    }
}

// ---------------- aggregation: one wave per node ----------------
__global__ __launch_bounds__(256) void agg_kernel(const unsigned short* __restrict__ h,
                                                  const int* __restrict__ rowstart,
                                                  const int* __restrict__ deg,
                                                  const float* __restrict__ inv_cnt,
                                                  const int* __restrict__ colidx,
                                                  unsigned short* __restrict__ mean) {
    int node = blockIdx.x * 4 + (threadIdx.x >> 6);
    int lane = threadIdx.x & 63;
    int start = rowstart[node];
    int d = deg[node];
    float a0 = 0.f, a1 = 0.f, a2 = 0.f, a3 = 0.f;
    int j = 0;
    for (; j + 4 <= d; j += 4) {
        int c0 = colidx[start + j + 0];
        int c1 = colidx[start + j + 1];
        int c2 = colidx[start + j + 2];
        int c3 = colidx[start + j + 3];
        ushort4 v0 = *(const ushort4*)&h[c0 * kH + lane * 4];
        ushort4 v1 = *(const ushort4*)&h[c1 * kH + lane * 4];
        ushort4 v2 = *(const ushort4*)&h[c2 * kH + lane * 4];
        ushort4 v3 = *(const ushort4*)&h[c3 * kH + lane * 4];
        a0 += b2f(v0.x) + b2f(v1.x) + b2f(v2.x) + b2f(v3.x);
        a1 += b2f(v0.y) + b2f(v1.y) + b2f(v2.y) + b2f(v3.y);
        a2 += b2f(v0.z) + b2f(v1.z) + b2f(v2.z) + b2f(v3.z);
        a3 += b2f(v0.w) + b2f(v1.w) + b2f(v2.w) + b2f(v3.w);
    }
    for (; j < d; ++j) {
        int c = colidx[start + j];
        ushort4 v = *(const ushort4*)&h[c * kH + lane * 4];
        a0 += b2f(v.x); a1 += b2f(v.y); a2 += b2f(v.z); a3 += b2f(v.w);
    }
    float ic = inv_cnt[node];
    ushort4 o;
    o.x = f2b(a0 * ic); o.y = f2b(a1 * ic); o.z = f2b(a2 * ic); o.w = f2b(a3 * ic);
    *(ushort4*)&mean[node * kH + lane * 4] = o;
}

// ---------------- fused GEMM: out = mean @ Wl^T + h @ Wr^T + b ----------------
#define BM 128
#define BN 64
#define BK 64
#define LDA 72
#define LDB 72

__global__ __launch_bounds__(256) void gemm_kernel(const unsigned short* __restrict__ mean,
                                                   const unsigned short* __restrict__ h,
                                                   const unsigned short* __restrict__ Wlb,
                                                   const unsigned short* __restrict__ Wrb,
                                                   const float* __restrict__ biasf,
                                                   unsigned short* __restrict__ hout,
                                                   float* __restrict__ foutf,
                                                   unsigned short* __restrict__ foutu,
                                                   const int* __restrict__ flags,
                                                   int is_final) {
    __shared__ __align__(16) unsigned short sA[BM * LDA];
    __shared__ __align__(16) unsigned short sB[BN * LDB];
    int bm0 = blockIdx.x * BM;
    int bn0 = blockIdx.y * BN;
    int tid = threadIdx.x;
    int wave = tid >> 6, lane = tid & 63;
    int quad = lane >> 4, r16 = lane & 15;

    f32x4 acc[2][4] = {};

    for (int kb = 0; kb < 512; kb += BK) {
        const unsigned short* Asrc = (kb < 256) ? mean : h;
        const unsigned short* Wsrc = (kb < 256) ? Wlb : Wrb;
        int kcol = kb & 255;
#pragma unroll
        for (int i = 0; i < 8; ++i) {
            int v = tid + i * 256;
            int row = v >> 4, c4 = (v & 15) * 4;
            int grow = bm0 + row;
            ushort4 val;
            if (grow < kN) val = *(const ushort4*)&Asrc[grow * kH + kcol + c4];
            else { val.x = val.y = val.z = val.w = 0; }
            *(ushort4*)&sA[row * LDA + c4] = val;
        }
#pragma unroll
        for (int i = 0; i < 4; ++i) {
            int v = tid + i * 256;
            int row = v >> 4, c4 = (v & 15) * 4;
            int gn = bn0 + row;
            *(ushort4*)&sB[row * LDB + c4] = *(const ushort4*)&Wsrc[gn * kH + kcol + c4];
        }
        __syncthreads();

#pragma unroll
        for (int ko = 0; ko < 2; ++ko) {
            bf16x8 af[2], bfv[4];
#pragma unroll
            for (int mt = 0; mt < 2; ++mt)
                af[mt] = *(const bf16x8*)&sA[(wave * 32 + mt * 16 + r16) * LDA + ko * 32 + quad * 8];
#pragma unroll
            for (int nt = 0; nt < 4; ++nt)
                bfv[nt] = *(const bf16x8*)&sB[(nt * 16 + r16) * LDB + ko * 32 + quad * 8];
#pragma unroll
            for (int mt = 0; mt < 2; ++mt)
#pragma unroll
                for (int nt = 0; nt < 4; ++nt)
                    acc[mt][nt] = __builtin_amdgcn_mfma_f32_16x16x32_bf16(
                        af[mt], bfv[nt], acc[mt][nt], 0, 0, 0);
        }
        __syncthreads();
    }

    int bf = is_bf(flags);
#pragma unroll
    for (int mt = 0; mt < 2; ++mt) {
        int mbase = bm0 + wave * 32 + mt * 16 + quad * 4;
#pragma unroll
        for (int nt = 0; nt < 4; ++nt) {
            int n = bn0 + nt * 16 + r16;
            float bv = biasf[n];
#pragma unroll
            for (int i = 0; i < 4; ++i) {
                int m = mbase + i;
                if (m < kN) {
                    float v = acc[mt][nt][i] + bv;
                    if (!is_final) {
                        v = fmaxf(v, 0.f);
                        hout[m * kH + n] = f2b(v);
                    } else if (bf) {
                        foutu[m * kH + n] = f2b(v);
                    } else {
                        foutf[m * kH + n] = v;
                    }
                }
            }
        }
    }
}

// ---------------- host ----------------
extern "C" void kernel_launch(void* const* d_in, const int* in_sizes, int n_in,
                              void* d_out, int out_size, void* d_ws, size_t ws_size,
                              hipStream_t stream) {
    const void* x  = d_in[0];
    const int*  ei = (const int*)d_in[1];
    const void* Wl = d_in[2];
    const void* Wr = d_in[3];
    const void* bb = d_in[4];

    char* p = (char*)d_ws;
    int*   flags    = (int*)p;   p += 1024;
    int*   colidx   = (int*)p;   p += (size_t)kE * 4;
    int*   rowstart = (int*)p;   p += (size_t)kN * 4;
    int*   deg      = (int*)p;   p += (size_t)kN * 4;
    int*   cursor   = (int*)p;   p += (size_t)kN * 4;
    float* inv_cnt  = (float*)p; p += (size_t)kN * 4;
    int*   blocksum = (int*)p;   p += 4096;
    float* biasf    = (float*)p; p += (size_t)kL * kH * 4;
    unsigned short* wlb   = (unsigned short*)p; p += (size_t)kL * kH * kH * 2;
    unsigned short* wrb   = (unsigned short*)p; p += (size_t)kL * kH * kH * 2;
    unsigned short* xb    = (unsigned short*)p; p += (size_t)kN * kH * 2;
    unsigned short* h0    = (unsigned short*)p; p += (size_t)kN * kH * 2;
    unsigned short* meanb = (unsigned short*)p; p += (size_t)kN * kH * 2;

    hipMemsetAsync(flags, 0, 1024, stream);
    hipMemsetAsync(deg, 0, (size_t)kN * 4, stream);

    detect_kernel<<<4096, 256, 0, stream>>>((const unsigned int*)ei,
                                            (const unsigned short*)x, flags);
    conv_x_kernel<<<(kN * kH / 4 + 255) / 256, 256, 0, stream>>>(x, xb, flags);
    conv_w_kernel<<<(kL * kH * kH / 4 + 255) / 256, 256, 0, stream>>>(Wl, Wr, wlb, wrb, flags);
    conv_b_kernel<<<1, 256, 0, stream>>>(bb, biasf, flags);

    hist_kernel<<<(kE + 255) / 256, 256, 0, stream>>>(ei, flags, deg);
    int nb = (kN + 1023) / 1024;
    scan1_kernel<<<nb, 256, 0, stream>>>(deg, rowstart, blocksum);
    scan2_kernel<<<1, 64, 0, stream>>>(blocksum, nb);
    scan3_kernel<<<(kN + 255) / 256, 256, 0, stream>>>(rowstart, blocksum, deg, cursor, inv_cnt);
    fill_kernel<<<(kE + 255) / 256, 256, 0, stream>>>(ei, flags, cursor, colidx);

    // rotation: l0: xb -> h0 ; l1: h0 -> xb ; l2: xb -> h0 ; l3: h0 -> d_out
    const unsigned short* hcur = xb;
    for (int l = 0; l < kL; ++l) {
        agg_kernel<<<kN / 4, 256, 0, stream>>>(hcur, rowstart, deg, inv_cnt, colidx, meanb);
        int is_final = (l == kL - 1);
        unsigned short* hout = (l & 1) ? xb : h0;
        gemm_kernel<<<dim3((kN + BM - 1) / BM, kH / BN), 256, 0, stream>>>(
            meanb, hcur,
            wlb + (size_t)l * kH * kH, wrb + (size_t)l * kH * kH,
            biasf + (size_t)l * kH,
            hout, (float*)d_out, (unsigned short*)d_out, flags, is_final);
        hcur = hout;
    }
}

// Round 3
// 1955.248 us; speedup vs baseline: 1.1811x; 1.1811x over previous
//
#include <hip/hip_runtime.h>

#define kN 100000
#define kH 256
#define kE 3200000
#define kL 4

typedef __attribute__((ext_vector_type(8))) short bf16x8;
typedef __attribute__((ext_vector_type(4))) float f32x4;

static __device__ __forceinline__ float b2f(unsigned short u) {
    return __uint_as_float(((unsigned int)u) << 16);
}
static __device__ __forceinline__ unsigned short f2b(float f) {
    unsigned int u = __float_as_uint(f);
    u = (u + 0x7fffu + ((u >> 16) & 1u)) >> 16;
    return (unsigned short)u;
}

// flags[0]: nonzero iff some sampled odd 32-bit word of edge buffer != 0 (=> int32 storage)
// flags[1]: count of sampled even-indexed ushorts of x with bf16-like exponent
//           (out of 65536 samples; > 32768 => floats stored as bf16)
static __device__ __forceinline__ int is_i64(const int* flags) { return flags[0] == 0; }
static __device__ __forceinline__ int is_bf(const int* flags) { return flags[1] > (1 << 15); }

static __device__ __forceinline__ int eidx(const int* __restrict__ ei, int i64, int pos) {
    return i64 ? ei[2 * pos] : ei[pos];
}

// ---------------- dtype detection (256 blocks x 256 threads = 2^16 samplers) --------
__global__ __launch_bounds__(256) void detect_kernel(const unsigned int* __restrict__ eiw,
                                                     const unsigned short* __restrict__ xu,
                                                     int* __restrict__ flags) {
    __shared__ int scount[4];
    int t = blockIdx.x * 256 + threadIdx.x;
    int lane = threadIdx.x & 63, wave = threadIdx.x >> 6;
    // edge probe: OR of ~1M odd words within first 8 MB (coalesced 16B-granule reads)
    unsigned int eor = 0;
#pragma unroll
    for (int j = 0; j < 16; ++j) eor |= eiw[(size_t)t * 32 + 2 * j + 1];
    for (int off = 32; off >= 1; off >>= 1) eor |= __shfl_down(eor, off);
    if (lane == 0 && eor) atomicOr(&flags[0], 1);
    // x storage census: ballot + popcount, one atomic per BLOCK
    unsigned short u = xu[2 * t];
    unsigned int e = (u >> 7) & 0xFF;
    unsigned long long m = __ballot(e >= 101 && e <= 140);
    if (lane == 0) scount[wave] = (int)__popcll(m);
    __syncthreads();
    if (threadIdx.x == 0)
        atomicAdd(&flags[1], scount[0] + scount[1] + scount[2] + scount[3]);
}

// ---------------- converters (branch on storage flavor) ----------------
__global__ __launch_bounds__(256) void conv_x_kernel(const void* __restrict__ x,
                                                     unsigned short* __restrict__ xb,
                                                     const int* __restrict__ flags) {
    int i = (blockIdx.x * 256 + threadIdx.x) * 4;  // over kN*kH = 25.6M
    if (is_bf(flags)) {
        *(ushort4*)&xb[i] = *(const ushort4*)&((const unsigned short*)x)[i];
    } else {
        float4 v = *(const float4*)&((const float*)x)[i];
        ushort4 o;
        o.x = f2b(v.x); o.y = f2b(v.y); o.z = f2b(v.z); o.w = f2b(v.w);
        *(ushort4*)&xb[i] = o;
    }
}

__global__ __launch_bounds__(256) void conv_w_kernel(const void* __restrict__ Wl,
                                                     const void* __restrict__ Wr,
                                                     unsigned short* __restrict__ wlb,
                                                     unsigned short* __restrict__ wrb,
                                                     const int* __restrict__ flags) {
    int i = (blockIdx.x * 256 + threadIdx.x) * 4;  // over kL*kH*kH = 262144
    if (is_bf(flags)) {
        *(ushort4*)&wlb[i] = *(const ushort4*)&((const unsigned short*)Wl)[i];
        *(ushort4*)&wrb[i] = *(const ushort4*)&((const unsigned short*)Wr)[i];
    } else {
        float4 a = *(const float4*)&((const float*)Wl)[i];
        float4 b = *(const float4*)&((const float*)Wr)[i];
        ushort4 oa, ob;
        oa.x = f2b(a.x); oa.y = f2b(a.y); oa.z = f2b(a.z); oa.w = f2b(a.w);
        ob.x = f2b(b.x); ob.y = f2b(b.y); ob.z = f2b(b.z); ob.w = f2b(b.w);
        *(ushort4*)&wlb[i] = oa;
        *(ushort4*)&wrb[i] = ob;
    }
}

__global__ __launch_bounds__(256) void conv_b_kernel(const void* __restrict__ b,
                                                     float* __restrict__ biasf,
                                                     const int* __restrict__ flags) {
    int i = threadIdx.x * 4;  // over kL*kH = 1024, single block
    if (is_bf(flags)) {
        ushort4 u = *(const ushort4*)&((const unsigned short*)b)[i];
        biasf[i + 0] = b2f(u.x); biasf[i + 1] = b2f(u.y);
        biasf[i + 2] = b2f(u.z); biasf[i + 3] = b2f(u.w);
    } else {
        *(float4*)&biasf[i] = *(const float4*)&((const float*)b)[i];
    }
}

// ---------------- CSR build ----------------
__global__ __launch_bounds__(256) void hist_kernel(const int* __restrict__ ei,
                                                   const int* __restrict__ flags,
                                                   int* __restrict__ deg) {
    int e = blockIdx.x * 256 + threadIdx.x;
    if (e < kE) atomicAdd(&deg[eidx(ei, is_i64(flags), kE + e)], 1);
}

__global__ __launch_bounds__(256) void scan1_kernel(const int* __restrict__ deg,
                                                    int* __restrict__ rowstart,
                                                    int* __restrict__ blocksum) {
    __shared__ int sdata[256];
    int t = threadIdx.x;
    int base = blockIdx.x * 1024 + t * 4;
    int v[4]; int s = 0;
#pragma unroll
    for (int i = 0; i < 4; ++i) {
        v[i] = (base + i < kN) ? deg[base + i] : 0;
        s += v[i];
    }
    sdata[t] = s;
    __syncthreads();
    for (int off = 1; off < 256; off <<= 1) {
        int x = (t >= off) ? sdata[t - off] : 0;
        __syncthreads();
        sdata[t] += x;
        __syncthreads();
    }
    int run = sdata[t] - s;
    if (t == 255) blocksum[blockIdx.x] = sdata[255];
#pragma unroll
    for (int i = 0; i < 4; ++i) {
        if (base + i < kN) rowstart[base + i] = run;
        run += v[i];
    }
}

__global__ void scan2_kernel(int* __restrict__ blocksum, int nb) {
    if (threadIdx.x == 0 && blockIdx.x == 0) {
        int acc = 0;
        for (int i = 0; i < nb; ++i) { int t = blocksum[i]; blocksum[i] = acc; acc += t; }
    }
}

__global__ __launch_bounds__(256) void scan3_kernel(int* __restrict__ rowstart,
                                                    const int* __restrict__ blocksum,
                                                    const int* __restrict__ deg,
                                                    int* __restrict__ cursor,
                                                    float* __restrict__ inv_cnt) {
    int i = blockIdx.x * 256 + threadIdx.x;
    if (i < kN) {
        int rs = rowstart[i] + blocksum[i >> 10];
        rowstart[i] = rs;
        cursor[i] = rs;
        int d = deg[i];
        inv_cnt[i] = 1.0f / (float)(d > 0 ? d : 1);
    }
}

__global__ __launch_bounds__(256) void fill_kernel(const int* __restrict__ ei,
                                                   const int* __restrict__ flags,
                                                   int* __restrict__ cursor,
                                                   int* __restrict__ colidx) {
    int e = blockIdx.x * 256 + threadIdx.x;
    if (e < kE) {
        int i64 = is_i64(flags);
        int s = eidx(ei, i64, e);
        int d = eidx(ei, i64, kE + e);
        int p = atomicAdd(&cursor[d], 1);
        colidx[p] = s;
    }
}

// ---------------- aggregation: one wave per node ----------------
__global__ __launch_bounds__(256) void agg_kernel(const unsigned short* __restrict__ h,
                                                  const int* __restrict__ rowstart,
                                                  const int* __restrict__ deg,
                                                  const float* __restrict__ inv_cnt,
                                                  const int* __restrict__ colidx,
                                                  unsigned short* __restrict__ mean) {
    int node = blockIdx.x * 4 + (threadIdx.x >> 6);
    int lane = threadIdx.x & 63;
    int start = rowstart[node];
    int d = deg[node];
    float a0 = 0.f, a1 = 0.f, a2 = 0.f, a3 = 0.f;
    int j = 0;
    for (; j + 4 <= d; j += 4) {
        int c0 = colidx[start + j + 0];
        int c1 = colidx[start + j + 1];
        int c2 = colidx[start + j + 2];
        int c3 = colidx[start + j + 3];
        ushort4 v0 = *(const ushort4*)&h[c0 * kH + lane * 4];
        ushort4 v1 = *(const ushort4*)&h[c1 * kH + lane * 4];
        ushort4 v2 = *(const ushort4*)&h[c2 * kH + lane * 4];
        ushort4 v3 = *(const ushort4*)&h[c3 * kH + lane * 4];
        a0 += b2f(v0.x) + b2f(v1.x) + b2f(v2.x) + b2f(v3.x);
        a1 += b2f(v0.y) + b2f(v1.y) + b2f(v2.y) + b2f(v3.y);
        a2 += b2f(v0.z) + b2f(v1.z) + b2f(v2.z) + b2f(v3.z);
        a3 += b2f(v0.w) + b2f(v1.w) + b2f(v2.w) + b2f(v3.w);
    }
    for (; j < d; ++j) {
        int c = colidx[start + j];
        ushort4 v = *(const ushort4*)&h[c * kH + lane * 4];
        a0 += b2f(v.x); a1 += b2f(v.y); a2 += b2f(v.z); a3 += b2f(v.w);
    }
    float ic = inv_cnt[node];
    ushort4 o;
    o.x = f2b(a0 * ic); o.y = f2b(a1 * ic); o.z = f2b(a2 * ic); o.w = f2b(a3 * ic);
    *(ushort4*)&mean[node * kH + lane * 4] = o;
}

// ---------------- fused GEMM: out = mean @ Wl^T + h @ Wr^T + b ----------------
#define BM 128
#define BN 64
#define BK 64
#define LDA 72
#define LDB 72

__global__ __launch_bounds__(256) void gemm_kernel(const unsigned short* __restrict__ mean,
                                                   const unsigned short* __restrict__ h,
                                                   const unsigned short* __restrict__ Wlb,
                                                   const unsigned short* __restrict__ Wrb,
                                                   const float* __restrict__ biasf,
                                                   unsigned short* __restrict__ hout,
                                                   float* __restrict__ foutf,
                                                   unsigned short* __restrict__ foutu,
                                                   const int* __restrict__ flags,
                                                   int is_final) {
    __shared__ __align__(16) unsigned short sA[BM * LDA];
    __shared__ __align__(16) unsigned short sB[BN * LDB];
    int bm0 = blockIdx.x * BM;
    int bn0 = blockIdx.y * BN;
    int tid = threadIdx.x;
    int wave = tid >> 6, lane = tid & 63;
    int quad = lane >> 4, r16 = lane & 15;

    f32x4 acc[2][4] = {};

    for (int kb = 0; kb < 512; kb += BK) {
        const unsigned short* Asrc = (kb < 256) ? mean : h;
        const unsigned short* Wsrc = (kb < 256) ? Wlb : Wrb;
        int kcol = kb & 255;
#pragma unroll
        for (int i = 0; i < 8; ++i) {
            int v = tid + i * 256;
            int row = v >> 4, c4 = (v & 15) * 4;
            int grow = bm0 + row;
            ushort4 val;
            if (grow < kN) val = *(const ushort4*)&Asrc[grow * kH + kcol + c4];
            else { val.x = val.y = val.z = val.w = 0; }
            *(ushort4*)&sA[row * LDA + c4] = val;
        }
#pragma unroll
        for (int i = 0; i < 4; ++i) {
            int v = tid + i * 256;
            int row = v >> 4, c4 = (v & 15) * 4;
            int gn = bn0 + row;
            *(ushort4*)&sB[row * LDB + c4] = *(const ushort4*)&Wsrc[gn * kH + kcol + c4];
        }
        __syncthreads();

#pragma unroll
        for (int ko = 0; ko < 2; ++ko) {
            bf16x8 af[2], bfv[4];
#pragma unroll
            for (int mt = 0; mt < 2; ++mt)
                af[mt] = *(const bf16x8*)&sA[(wave * 32 + mt * 16 + r16) * LDA + ko * 32 + quad * 8];
#pragma unroll
            for (int nt = 0; nt < 4; ++nt)
                bfv[nt] = *(const bf16x8*)&sB[(nt * 16 + r16) * LDB + ko * 32 + quad * 8];
#pragma unroll
            for (int mt = 0; mt < 2; ++mt)
#pragma unroll
                for (int nt = 0; nt < 4; ++nt)
                    acc[mt][nt] = __builtin_amdgcn_mfma_f32_16x16x32_bf16(
                        af[mt], bfv[nt], acc[mt][nt], 0, 0, 0);
        }
        __syncthreads();
    }

    int bf = is_bf(flags);
#pragma unroll
    for (int mt = 0; mt < 2; ++mt) {
        int mbase = bm0 + wave * 32 + mt * 16 + quad * 4;
#pragma unroll
        for (int nt = 0; nt < 4; ++nt) {
            int n = bn0 + nt * 16 + r16;
            float bv = biasf[n];
#pragma unroll
            for (int i = 0; i < 4; ++i) {
                int m = mbase + i;
                if (m < kN) {
                    float v = acc[mt][nt][i] + bv;
                    if (!is_final) {
                        v = fmaxf(v, 0.f);
                        hout[m * kH + n] = f2b(v);
                    } else if (bf) {
                        foutu[m * kH + n] = f2b(v);
                    } else {
                        foutf[m * kH + n] = v;
                    }
                }
            }
        }
    }
}

// ---------------- host ----------------
extern "C" void kernel_launch(void* const* d_in, const int* in_sizes, int n_in,
                              void* d_out, int out_size, void* d_ws, size_t ws_size,
                              hipStream_t stream) {
    const void* x  = d_in[0];
    const int*  ei = (const int*)d_in[1];
    const void* Wl = d_in[2];
    const void* Wr = d_in[3];
    const void* bb = d_in[4];

    char* p = (char*)d_ws;
    int*   flags    = (int*)p;   p += 1024;
    int*   colidx   = (int*)p;   p += (size_t)kE * 4;
    int*   rowstart = (int*)p;   p += (size_t)kN * 4;
    int*   deg      = (int*)p;   p += (size_t)kN * 4;
    int*   cursor   = (int*)p;   p += (size_t)kN * 4;
    float* inv_cnt  = (float*)p; p += (size_t)kN * 4;
    int*   blocksum = (int*)p;   p += 4096;
    float* biasf    = (float*)p; p += (size_t)kL * kH * 4;
    unsigned short* wlb   = (unsigned short*)p; p += (size_t)kL * kH * kH * 2;
    unsigned short* wrb   = (unsigned short*)p; p += (size_t)kL * kH * kH * 2;
    unsigned short* xb    = (unsigned short*)p; p += (size_t)kN * kH * 2;
    unsigned short* h0    = (unsigned short*)p; p += (size_t)kN * kH * 2;
    unsigned short* meanb = (unsigned short*)p; p += (size_t)kN * kH * 2;

    hipMemsetAsync(flags, 0, 1024, stream);
    hipMemsetAsync(deg, 0, (size_t)kN * 4, stream);

    detect_kernel<<<256, 256, 0, stream>>>((const unsigned int*)ei,
                                           (const unsigned short*)x, flags);
    conv_x_kernel<<<(kN * kH / 4 + 255) / 256, 256, 0, stream>>>(x, xb, flags);
    conv_w_kernel<<<(kL * kH * kH / 4 + 255) / 256, 256, 0, stream>>>(Wl, Wr, wlb, wrb, flags);
    conv_b_kernel<<<1, 256, 0, stream>>>(bb, biasf, flags);

    hist_kernel<<<(kE + 255) / 256, 256, 0, stream>>>(ei, flags, deg);
    int nb = (kN + 1023) / 1024;
    scan1_kernel<<<nb, 256, 0, stream>>>(deg, rowstart, blocksum);
    scan2_kernel<<<1, 64, 0, stream>>>(blocksum, nb);
    scan3_kernel<<<(kN + 255) / 256, 256, 0, stream>>>(rowstart, blocksum, deg, cursor, inv_cnt);
    fill_kernel<<<(kE + 255) / 256, 256, 0, stream>>>(ei, flags, cursor, colidx);

    // rotation: l0: xb -> h0 ; l1: h0 -> xb ; l2: xb -> h0 ; l3: h0 -> d_out
    const unsigned short* hcur = xb;
    for (int l = 0; l < kL; ++l) {
        agg_kernel<<<kN / 4, 256, 0, stream>>>(hcur, rowstart, deg, inv_cnt, colidx, meanb);
        int is_final = (l == kL - 1);
        unsigned short* hout = (l & 1) ? xb : h0;
        gemm_kernel<<<dim3((kN + BM - 1) / BM, kH / BN), 256, 0, stream>>>(
            meanb, hcur,
            wlb + (size_t)l * kH * kH, wrb + (size_t)l * kH * kH,
            biasf + (size_t)l * kH,
            hout, (float*)d_out, (unsigned short*)d_out, flags, is_final);
        hcur = hout;
    }
}

// Round 4
// 1651.637 us; speedup vs baseline: 1.3982x; 1.1838x over previous
//
#include <hip/hip_runtime.h>

#define kN 100000
#define kH 256
#define kE 3200000
#define kL 4

// binning: bucket = dst >> 8 (256 nodes/bucket), EPB edges per binning block
#define NB   391          // ceil(kN / 256)
#define EPB  8192
#define NBLK 391          // ceil(kE / EPB)
#define NC   (NB * NBLK)  // 152881 counters

typedef __attribute__((ext_vector_type(8))) short bf16x8;
typedef __attribute__((ext_vector_type(4))) float f32x4;

static __device__ __forceinline__ float b2f(unsigned short u) {
    return __uint_as_float(((unsigned int)u) << 16);
}
static __device__ __forceinline__ unsigned short f2b(float f) {
    unsigned int u = __float_as_uint(f);
    u = (u + 0x7fffu + ((u >> 16) & 1u)) >> 16;
    return (unsigned short)u;
}

// flags[0]: nonzero iff some sampled odd 32-bit word of edge buffer != 0 (=> int32 storage)
// flags[1]: count of sampled even ushorts of x with bf16-like exponent (of 65536)
static __device__ __forceinline__ int is_i64(const int* flags) { return flags[0] == 0; }
static __device__ __forceinline__ int is_bf(const int* flags) { return flags[1] > (1 << 15); }

static __device__ __forceinline__ int eidx(const int* __restrict__ ei, int i64, int pos) {
    return i64 ? ei[2 * pos] : ei[pos];
}

// ---------------- dtype detection ----------------
__global__ __launch_bounds__(256) void detect_kernel(const unsigned int* __restrict__ eiw,
                                                     const unsigned short* __restrict__ xu,
                                                     int* __restrict__ flags) {
    __shared__ int scount[4];
    int t = blockIdx.x * 256 + threadIdx.x;
    int lane = threadIdx.x & 63, wave = threadIdx.x >> 6;
    unsigned int eor = 0;
#pragma unroll
    for (int j = 0; j < 16; ++j) eor |= eiw[(size_t)t * 32 + 2 * j + 1];
    for (int off = 32; off >= 1; off >>= 1) eor |= __shfl_down(eor, off);
    if (lane == 0 && eor) atomicOr(&flags[0], 1);
    unsigned short u = xu[2 * t];
    unsigned int e = (u >> 7) & 0xFF;
    unsigned long long m = __ballot(e >= 101 && e <= 140);
    if (lane == 0) scount[wave] = (int)__popcll(m);
    __syncthreads();
    if (threadIdx.x == 0)
        atomicAdd(&flags[1], scount[0] + scount[1] + scount[2] + scount[3]);
}

// ---------------- converters ----------------
__global__ __launch_bounds__(256) void conv_x_kernel(const void* __restrict__ x,
                                                     unsigned short* __restrict__ xb,
                                                     const int* __restrict__ flags) {
    int i = (blockIdx.x * 256 + threadIdx.x) * 4;
    if (is_bf(flags)) {
        *(ushort4*)&xb[i] = *(const ushort4*)&((const unsigned short*)x)[i];
    } else {
        float4 v = *(const float4*)&((const float*)x)[i];
        ushort4 o;
        o.x = f2b(v.x); o.y = f2b(v.y); o.z = f2b(v.z); o.w = f2b(v.w);
        *(ushort4*)&xb[i] = o;
    }
}

__global__ __launch_bounds__(256) void conv_w_kernel(const void* __restrict__ Wl,
                                                     const void* __restrict__ Wr,
                                                     unsigned short* __restrict__ wlb,
                                                     unsigned short* __restrict__ wrb,
                                                     const int* __restrict__ flags) {
    int i = (blockIdx.x * 256 + threadIdx.x) * 4;
    if (is_bf(flags)) {
        *(ushort4*)&wlb[i] = *(const ushort4*)&((const unsigned short*)Wl)[i];
        *(ushort4*)&wrb[i] = *(const ushort4*)&((const unsigned short*)Wr)[i];
    } else {
        float4 a = *(const float4*)&((const float*)Wl)[i];
        float4 b = *(const float4*)&((const float*)Wr)[i];
        ushort4 oa, ob;
        oa.x = f2b(a.x); oa.y = f2b(a.y); oa.z = f2b(a.z); oa.w = f2b(a.w);
        ob.x = f2b(b.x); ob.y = f2b(b.y); ob.z = f2b(b.z); ob.w = f2b(b.w);
        *(ushort4*)&wlb[i] = oa;
        *(ushort4*)&wrb[i] = ob;
    }
}

__global__ __launch_bounds__(256) void conv_b_kernel(const void* __restrict__ b,
                                                     float* __restrict__ biasf,
                                                     const int* __restrict__ flags) {
    int i = threadIdx.x * 4;
    if (is_bf(flags)) {
        ushort4 u = *(const ushort4*)&((const unsigned short*)b)[i];
        biasf[i + 0] = b2f(u.x); biasf[i + 1] = b2f(u.y);
        biasf[i + 2] = b2f(u.z); biasf[i + 3] = b2f(u.w);
    } else {
        *(float4*)&biasf[i] = *(const float4*)&((const float*)b)[i];
    }
}

// ---------------- binned CSR build ----------------
// A: per-block bucket histogram -> counts[bucket*NBLK + blk]
__global__ __launch_bounds__(256) void binA_kernel(const int* __restrict__ ei,
                                                   const int* __restrict__ flags,
                                                   int* __restrict__ counts) {
    __shared__ int hist[NB];
    for (int i = threadIdx.x; i < NB; i += 256) hist[i] = 0;
    __syncthreads();
    int i64 = is_i64(flags);
    int base = blockIdx.x * EPB;
    int end = min(kE, base + EPB);
    for (int e = base + threadIdx.x; e < end; e += 256)
        atomicAdd(&hist[eidx(ei, i64, kE + e) >> 8], 1);
    __syncthreads();
    for (int i = threadIdx.x; i < NB; i += 256)
        counts[i * NBLK + blockIdx.x] = hist[i];
}

// exclusive scan over NC counters (1024/block, proven scan1 pattern)
__global__ __launch_bounds__(256) void gscan1_kernel(const int* __restrict__ counts,
                                                     int* __restrict__ offs,
                                                     int* __restrict__ blocksum) {
    __shared__ int sdata[256];
    int t = threadIdx.x;
    int base = blockIdx.x * 1024 + t * 4;
    int v[4]; int s = 0;
#pragma unroll
    for (int i = 0; i < 4; ++i) {
        v[i] = (base + i < NC) ? counts[base + i] : 0;
        s += v[i];
    }
    sdata[t] = s;
    __syncthreads();
    for (int off = 1; off < 256; off <<= 1) {
        int x = (t >= off) ? sdata[t - off] : 0;
        __syncthreads();
        sdata[t] += x;
        __syncthreads();
    }
    int run = sdata[t] - s;
    if (t == 255) blocksum[blockIdx.x] = sdata[255];
#pragma unroll
    for (int i = 0; i < 4; ++i) {
        if (base + i < NC) offs[base + i] = run;
        run += v[i];
    }
}

__global__ void gscan2_kernel(int* __restrict__ blocksum, int nb) {
    if (threadIdx.x == 0 && blockIdx.x == 0) {
        int acc = 0;
        for (int i = 0; i < nb; ++i) { int t = blocksum[i]; blocksum[i] = acc; acc += t; }
    }
}

__global__ __launch_bounds__(256) void gscan3_kernel(int* __restrict__ offs,
                                                     const int* __restrict__ blocksum) {
    int i = blockIdx.x * 256 + threadIdx.x;
    if (i < NC) offs[i] += blocksum[i >> 10];
}

// C: scatter (src,dst) into bucket-sorted pairs array
__global__ __launch_bounds__(256) void binC_kernel(const int* __restrict__ ei,
                                                   const int* __restrict__ flags,
                                                   const int* __restrict__ offs,
                                                   uint2* __restrict__ pairs) {
    __shared__ int cur[NB];
    for (int i = threadIdx.x; i < NB; i += 256)
        cur[i] = offs[i * NBLK + blockIdx.x];
    __syncthreads();
    int i64 = is_i64(flags);
    int base = blockIdx.x * EPB;
    int end = min(kE, base + EPB);
    for (int e = base + threadIdx.x; e < end; e += 256) {
        int s = eidx(ei, i64, e);
        int d = eidx(ei, i64, kE + e);
        int p = atomicAdd(&cur[d >> 8], 1);
        uint2 pr; pr.x = (unsigned)s; pr.y = (unsigned)d;
        pairs[p] = pr;
    }
}

// D: per-bucket: node histogram + LDS scan -> deg/rowstart/inv_cnt + colidx fill
__global__ __launch_bounds__(256) void binD_kernel(const uint2* __restrict__ pairs,
                                                   const int* __restrict__ offs,
                                                   int* __restrict__ rowstart,
                                                   int* __restrict__ deg,
                                                   float* __restrict__ inv_cnt,
                                                   int* __restrict__ colidx) {
    __shared__ int cnt[256];
    __shared__ int sdata[256];
    __shared__ int cur[256];
    int b = blockIdx.x;
    int t = threadIdx.x;
    int node0 = b << 8;
    int Ob = offs[b * NBLK];
    int Oe = (b + 1 < NB) ? offs[(b + 1) * NBLK] : kE;
    cnt[t] = 0;
    __syncthreads();
    for (int i = Ob + t; i < Oe; i += 256)
        atomicAdd(&cnt[pairs[i].y - node0], 1);
    __syncthreads();
    // exclusive scan of cnt
    int v = cnt[t];
    sdata[t] = v;
    __syncthreads();
    for (int off = 1; off < 256; off <<= 1) {
        int x = (t >= off) ? sdata[t - off] : 0;
        __syncthreads();
        sdata[t] += x;
        __syncthreads();
    }
    int pfx = sdata[t] - v;  // exclusive
    int node = node0 + t;
    if (node < kN) {
        rowstart[node] = Ob + pfx;
        deg[node] = v;
        inv_cnt[node] = 1.0f / (float)(v > 0 ? v : 1);
    }
    cur[t] = Ob + pfx;
    __syncthreads();
    for (int i = Ob + t; i < Oe; i += 256) {
        uint2 pr = pairs[i];
        int p = atomicAdd(&cur[pr.y - node0], 1);
        colidx[p] = (int)pr.x;
    }
}

// ---------------- aggregation: one wave per node ----------------
__global__ __launch_bounds__(256) void agg_kernel(const unsigned short* __restrict__ h,
                                                  const int* __restrict__ rowstart,
                                                  const int* __restrict__ deg,
                                                  const float* __restrict__ inv_cnt,
                                                  const int* __restrict__ colidx,
                                                  unsigned short* __restrict__ mean) {
    int node = blockIdx.x * 4 + (threadIdx.x >> 6);
    int lane = threadIdx.x & 63;
    int start = rowstart[node];
    int d = deg[node];
    float a0 = 0.f, a1 = 0.f, a2 = 0.f, a3 = 0.f;
    int j = 0;
    for (; j + 4 <= d; j += 4) {
        int c0 = colidx[start + j + 0];
        int c1 = colidx[start + j + 1];
        int c2 = colidx[start + j + 2];
        int c3 = colidx[start + j + 3];
        ushort4 v0 = *(const ushort4*)&h[c0 * kH + lane * 4];
        ushort4 v1 = *(const ushort4*)&h[c1 * kH + lane * 4];
        ushort4 v2 = *(const ushort4*)&h[c2 * kH + lane * 4];
        ushort4 v3 = *(const ushort4*)&h[c3 * kH + lane * 4];
        a0 += b2f(v0.x) + b2f(v1.x) + b2f(v2.x) + b2f(v3.x);
        a1 += b2f(v0.y) + b2f(v1.y) + b2f(v2.y) + b2f(v3.y);
        a2 += b2f(v0.z) + b2f(v1.z) + b2f(v2.z) + b2f(v3.z);
        a3 += b2f(v0.w) + b2f(v1.w) + b2f(v2.w) + b2f(v3.w);
    }
    for (; j < d; ++j) {
        int c = colidx[start + j];
        ushort4 v = *(const ushort4*)&h[c * kH + lane * 4];
        a0 += b2f(v.x); a1 += b2f(v.y); a2 += b2f(v.z); a3 += b2f(v.w);
    }
    float ic = inv_cnt[node];
    ushort4 o;
    o.x = f2b(a0 * ic); o.y = f2b(a1 * ic); o.z = f2b(a2 * ic); o.w = f2b(a3 * ic);
    *(ushort4*)&mean[node * kH + lane * 4] = o;
}

// ---------------- fused GEMM: out = mean @ Wl^T + h @ Wr^T + b ----------------
#define BM 128
#define BN 64
#define BK 64
#define LDA 72
#define LDB 72

__global__ __launch_bounds__(256) void gemm_kernel(const unsigned short* __restrict__ mean,
                                                   const unsigned short* __restrict__ h,
                                                   const unsigned short* __restrict__ Wlb,
                                                   const unsigned short* __restrict__ Wrb,
                                                   const float* __restrict__ biasf,
                                                   unsigned short* __restrict__ hout,
                                                   float* __restrict__ foutf,
                                                   unsigned short* __restrict__ foutu,
                                                   const int* __restrict__ flags,
                                                   int is_final) {
    __shared__ __align__(16) unsigned short sA[BM * LDA];
    __shared__ __align__(16) unsigned short sB[BN * LDB];
    int bm0 = blockIdx.x * BM;
    int bn0 = blockIdx.y * BN;
    int tid = threadIdx.x;
    int wave = tid >> 6, lane = tid & 63;
    int quad = lane >> 4, r16 = lane & 15;

    f32x4 acc[2][4] = {};

    for (int kb = 0; kb < 512; kb += BK) {
        const unsigned short* Asrc = (kb < 256) ? mean : h;
        const unsigned short* Wsrc = (kb < 256) ? Wlb : Wrb;
        int kcol = kb & 255;
#pragma unroll
        for (int i = 0; i < 8; ++i) {
            int v = tid + i * 256;
            int row = v >> 4, c4 = (v & 15) * 4;
            int grow = bm0 + row;
            ushort4 val;
            if (grow < kN) val = *(const ushort4*)&Asrc[grow * kH + kcol + c4];
            else { val.x = val.y = val.z = val.w = 0; }
            *(ushort4*)&sA[row * LDA + c4] = val;
        }
#pragma unroll
        for (int i = 0; i < 4; ++i) {
            int v = tid + i * 256;
            int row = v >> 4, c4 = (v & 15) * 4;
            int gn = bn0 + row;
            *(ushort4*)&sB[row * LDB + c4] = *(const ushort4*)&Wsrc[gn * kH + kcol + c4];
        }
        __syncthreads();

#pragma unroll
        for (int ko = 0; ko < 2; ++ko) {
            bf16x8 af[2], bfv[4];
#pragma unroll
            for (int mt = 0; mt < 2; ++mt)
                af[mt] = *(const bf16x8*)&sA[(wave * 32 + mt * 16 + r16) * LDA + ko * 32 + quad * 8];
#pragma unroll
            for (int nt = 0; nt < 4; ++nt)
                bfv[nt] = *(const bf16x8*)&sB[(nt * 16 + r16) * LDB + ko * 32 + quad * 8];
#pragma unroll
            for (int mt = 0; mt < 2; ++mt)
#pragma unroll
                for (int nt = 0; nt < 4; ++nt)
                    acc[mt][nt] = __builtin_amdgcn_mfma_f32_16x16x32_bf16(
                        af[mt], bfv[nt], acc[mt][nt], 0, 0, 0);
        }
        __syncthreads();
    }

    int bf = is_bf(flags);
#pragma unroll
    for (int mt = 0; mt < 2; ++mt) {
        int mbase = bm0 + wave * 32 + mt * 16 + quad * 4;
#pragma unroll
        for (int nt = 0; nt < 4; ++nt) {
            int n = bn0 + nt * 16 + r16;
            float bv = biasf[n];
#pragma unroll
            for (int i = 0; i < 4; ++i) {
                int m = mbase + i;
                if (m < kN) {
                    float v = acc[mt][nt][i] + bv;
                    if (!is_final) {
                        v = fmaxf(v, 0.f);
                        hout[m * kH + n] = f2b(v);
                    } else if (bf) {
                        foutu[m * kH + n] = f2b(v);
                    } else {
                        foutf[m * kH + n] = v;
                    }
                }
            }
        }
    }
}

// ---------------- host ----------------
extern "C" void kernel_launch(void* const* d_in, const int* in_sizes, int n_in,
                              void* d_out, int out_size, void* d_ws, size_t ws_size,
                              hipStream_t stream) {
    const void* x  = d_in[0];
    const int*  ei = (const int*)d_in[1];
    const void* Wl = d_in[2];
    const void* Wr = d_in[3];
    const void* bb = d_in[4];

    char* p = (char*)d_ws;
    int*   flags    = (int*)p;   p += 1024;
    int*   colidx   = (int*)p;   p += (size_t)kE * 4;
    int*   rowstart = (int*)p;   p += (size_t)kN * 4;
    int*   deg      = (int*)p;   p += (size_t)kN * 4;
    float* inv_cnt  = (float*)p; p += (size_t)kN * 4;
    int*   blocksum = (int*)p;   p += 4096;
    float* biasf    = (float*)p; p += (size_t)kL * kH * 4;
    unsigned short* wlb   = (unsigned short*)p; p += (size_t)kL * kH * kH * 2;
    unsigned short* wrb   = (unsigned short*)p; p += (size_t)kL * kH * kH * 2;
    unsigned short* xb    = (unsigned short*)p; p += (size_t)kN * kH * 2;
    unsigned short* h0    = (unsigned short*)p; p += (size_t)kN * kH * 2;
    unsigned short* meanb = (unsigned short*)p; p += (size_t)kN * kH * 2;

    // aliases (dead until layer 0 starts): pairs on meanb, counts/offs on h0
    uint2* pairs  = (uint2*)meanb;                 // 25.6 MB <= 51.2 MB
    int*   counts = (int*)h0;                      // NC*4 = 0.61 MB
    int*   offs   = (int*)h0 + NC;                 // NC*4

    hipMemsetAsync(flags, 0, 1024, stream);

    detect_kernel<<<256, 256, 0, stream>>>((const unsigned int*)ei,
                                           (const unsigned short*)x, flags);
    conv_x_kernel<<<(kN * kH / 4 + 255) / 256, 256, 0, stream>>>(x, xb, flags);
    conv_w_kernel<<<(kL * kH * kH / 4 + 255) / 256, 256, 0, stream>>>(Wl, Wr, wlb, wrb, flags);
    conv_b_kernel<<<1, 256, 0, stream>>>(bb, biasf, flags);

    binA_kernel<<<NBLK, 256, 0, stream>>>(ei, flags, counts);
    int nb2 = (NC + 1023) / 1024;
    gscan1_kernel<<<nb2, 256, 0, stream>>>(counts, offs, blocksum);
    gscan2_kernel<<<1, 64, 0, stream>>>(blocksum, nb2);
    gscan3_kernel<<<(NC + 255) / 256, 256, 0, stream>>>(offs, blocksum);
    binC_kernel<<<NBLK, 256, 0, stream>>>(ei, flags, offs, pairs);
    binD_kernel<<<NB, 256, 0, stream>>>(pairs, offs, rowstart, deg, inv_cnt, colidx);

    // rotation: l0: xb -> h0 ; l1: h0 -> xb ; l2: xb -> h0 ; l3: h0 -> d_out
    const unsigned short* hcur = xb;
    for (int l = 0; l < kL; ++l) {
        agg_kernel<<<kN / 4, 256, 0, stream>>>(hcur, rowstart, deg, inv_cnt, colidx, meanb);
        int is_final = (l == kL - 1);
        unsigned short* hout = (l & 1) ? xb : h0;
        gemm_kernel<<<dim3((kN + BM - 1) / BM, kH / BN), 256, 0, stream>>>(
            meanb, hcur,
            wlb + (size_t)l * kH * kH, wrb + (size_t)l * kH * kH,
            biasf + (size_t)l * kH,
            hout, (float*)d_out, (unsigned short*)d_out, flags, is_final);
        hcur = hout;
    }
}